// Round 6
// baseline (437.064 us; speedup 1.0000x reference)
//
#include <hip/hip_runtime.h>
#include <hip/hip_bf16.h>
#include <stdint.h>

// ---- problem constants ----
#define N_IMG 32
#define C_IN  256
#define HW    56
#define PIX   3136            // 56*56
#define M_TOT 100352          // 32*3136
#define C_OUT 256
#define K_TOT 2304            // 256*9
#define HP    58
#define WPAD  58
#define OUT_IMG_STRIDE 802816 // 256*3136

// ---- GEMM tile config: BM=64 (one image, 64-px tile), BN=256 (all couts) ----
// 3136 = 64*49 -> 49 px-tiles/image, no image-crossing. Wave = 64m x 64n
// (f_m = f_n = 4): balanced reuse -> A-LDS 62% of MFMA-cy, 64 AGPR/wave.
#define BM 64
#define BN 256
#define SLAB_ROWS 5                  // window rows: 64 px span <=3 image rows +2 halo
#define SLAB_PIX  (SLAB_ROWS * 58)   // 290
#define SLAB_SLOTS (SLAB_PIX * 4)    // 1160 16B slots (32 chans/pixel, 4 parts of 8)

typedef __attribute__((ext_vector_type(8))) short bf16x8_t;   // 8 bf16 = 4 VGPRs
typedef __attribute__((ext_vector_type(4))) float f32x4_t;

// ---------------- pass 0: zero only the padded border (3.7 MB, not 55 MB) -----------
__global__ void border_zero_kernel(__hip_bfloat16* __restrict__ xpad) {
    int t = blockIdx.x * 256 + threadIdx.x;   // 32 n * 228 border px * 32 uint4 = 233472
    if (t >= 32 * 228 * 32) return;
    int n = t / (228 * 32);
    int r = t - n * (228 * 32);
    int px = r >> 5, part = r & 31;
    int hp, wp;
    if (px < 58)       { hp = 0;  wp = px; }
    else if (px < 116) { hp = 57; wp = px - 116 + 58; }
    else { int k = px - 116; hp = 1 + (k >> 1); wp = (k & 1) ? 57 : 0; }
    long e = (((long)n * HP + hp) * WPAD + wp) * C_IN + part * 8;
    *(uint4*)(xpad + e) = make_uint4(0u, 0u, 0u, 0u);
}

// ---------------- pass 1: NCHW fp32 -> padded NHWC bf16 transpose --------------------
__global__ void xform_kernel(const float* __restrict__ x, __hip_bfloat16* __restrict__ xpad) {
    __shared__ float tile[64][65];
    int b   = blockIdx.x;
    int n   = b / 196;
    int rem = b - n * 196;
    int ct  = rem / 49;
    int pt  = rem - ct * 49;
    int c0 = ct * 64, p0 = pt * 64;
    int t = threadIdx.x;

    const float* xs = x + (size_t)n * C_IN * PIX;
    int pc = t & 63, cr = t >> 6;   // read: coalesced along pixels
#pragma unroll
    for (int it = 0; it < 16; ++it) {
        int c = c0 + it * 4 + cr;
        tile[it * 4 + cr][pc] = xs[(size_t)c * PIX + p0 + pc];
    }
    __syncthreads();
    int cl = t & 63, pr = t >> 6;   // write: coalesced along channels
#pragma unroll
    for (int it = 0; it < 16; ++it) {
        int p = p0 + it * 4 + pr;
        int h = p / HW, w = p - h * HW;
        float v = tile[cl][it * 4 + pr];
        xpad[(((size_t)n * HP + (h + 1)) * WPAD + (w + 1)) * C_IN + c0 + cl] = __float2bfloat16(v);
    }
}

// ---------------- pass 2: binarize + transpose weights -> wt[cout][tap][c] bf16 -------
__global__ void wxform_kernel(const float* __restrict__ w, __hip_bfloat16* __restrict__ wt) {
    int i = blockIdx.x * 256 + threadIdx.x;   // over 589824
    if (i >= C_OUT * K_TOT) return;
    int cout = i / K_TOT;
    int r    = i - cout * K_TOT;
    int tap  = r >> 8;
    int c    = r & 255;
    float v = w[cout * 2304 + c * 9 + tap];   // [cout][cin][3][3]
    float s = (v > 0.f) ? 1.f : ((v < 0.f) ? -1.f : 0.f);
    wt[i] = __float2bfloat16(s);
}

// ---------------- pass 3: balanced-reuse implicit-GEMM MFMA conv ---------------------
// v7: occupancy via workgroup granularity + balanced f_m=f_n=4.
//  - 256 threads = 4 waves, each wave = full 64 M-rows x 64 couts (acc[4][4] =
//    64 AGPR; each a-read feeds 4 MFMA, each b-read feeds 4 MFMA).
//  - ~60 arch VGPR + 64 AGPR ~ 124/wave; __launch_bounds__(256,3) guarantees a
//    170-reg budget (NO forced spill -- v6's launch_bounds(512,4) spilled:
//    VGPR pinned at 64, +54MB scratch writes, L3 thrashed). 4-wave blocks give
//    12 waves/CU at <=170 regs (16 if allocator lands <=128).
//  - slab: 5 padded rows x 58 x 32ch = 18.6 KB, v5-verified XOR-swizzle
//    (slot (p,q) holds chan-part q^((p>>1)&3)); same 2-barrier chunk loop
//    (rounds 1-4: all explicit scheduling null at this occupancy; rely on
//    m114 implicit inter-block overlap, now 3 blocks/CU).
__global__ void __launch_bounds__(256, 3)
gemm_kernel(const __hip_bfloat16* __restrict__ xpad,
            const __hip_bfloat16* __restrict__ wt,
            const float* __restrict__ bias,
            float* __restrict__ out) {
    __shared__ __hip_bfloat16 slab[SLAB_PIX * 32];   // 18560 B

    // bijective XCD swizzle: 1568 = 8*196; each XCD gets 196 consecutive
    // (image, pt) tiles -> window-row overlap between neighbor pt stays in-XCD.
    int bx = blockIdx.x;
    int b2 = (bx & 7) * 196 + (bx >> 3);
    int n  = b2 / 49;                    // image
    int pt = b2 - n * 49;                // 64-px tile within image
    int rA = (8 * pt) / 7;               // first padded row of window ((64pt)/56)

    int tid = threadIdx.x, lane = tid & 63, wn = tid >> 6;   // 4 waves: wn 0..3
    int ar = lane & 15;
    int kq = lane >> 4;                  // 0..3 (chan-part within 32-chan chunk)

    // a-frag slab pixel bases for tap (0,0): m = i*16 + ar (whole BM per wave)
    int lp0[4];
#pragma unroll
    for (int i = 0; i < 4; ++i) {
        int px = pt * 64 + i * 16 + ar;
        int r = px / 56, c = px - r * 56;
        lp0[i] = (r - rA) * 58 + c;
    }
    // per-lane B bases (elems into wt): wave covers couts wn*64 .. +63
    int wb[4];
#pragma unroll
    for (int j = 0; j < 4; ++j)
        wb[j] = (wn * 64 + j * 16 + ar) * K_TOT + kq * 8;

    // staging precompute: per-iter global element index (sans ch*32).
    // slot s=(p,q): linear LDS byte s*16 holds chan-part q^((p>>1)&3) of
    // window pixel p (p = dr*58+wc, padded row rA+dr).
    int gi[5];
#pragma unroll
    for (int it = 0; it < 5; ++it) {
        int s = it * 256 + tid;
        int p = s >> 2, q = s & 3;
        int dr = p / 58, wc = p - dr * 58;
        int qs = q ^ ((p >> 1) & 3);
        gi[it] = ((n * HP + rA + dr) * WPAD + wc) * C_IN + qs * 8;
    }

    f32x4_t acc[4][4] = {};

    for (int ch = 0; ch < 8; ++ch) {
        if (ch) __syncthreads();
#pragma unroll
        for (int it = 0; it < 5; ++it) {
            int s = it * 256 + tid;
            if (it < 4 || s < SLAB_SLOTS) {
                uint4 v = *(const uint4*)(xpad + (long)gi[it] + ch * 32);
                *(uint4*)((char*)slab + s * 16) = v;
            }
        }
        __syncthreads();

#pragma unroll
        for (int t = 0; t < 9; ++t) {
            const int kh = t / 3, kw = t - kh * 3;
            const int dpx = kh * 58 + kw;
            bf16x8_t b[4];
#pragma unroll
            for (int j = 0; j < 4; ++j)
                b[j] = *(const bf16x8_t*)&wt[wb[j] + t * 256 + ch * 32];
            bf16x8_t a[4];
#pragma unroll
            for (int i = 0; i < 4; ++i) {
                int p = lp0[i] + dpx;
                int off = (p << 5) + ((kq ^ ((p >> 1) & 3)) << 3);   // elems
                a[i] = *(const bf16x8_t*)&slab[off];
            }
#pragma unroll
            for (int i = 0; i < 4; ++i)
#pragma unroll
                for (int j = 0; j < 4; ++j)
                    acc[i][j] = __builtin_amdgcn_mfma_f32_16x16x32_bf16(a[i], b[j], acc[i][j], 0, 0, 0);
        }
    }

    // epilogue: C/D col=lane&15 (n), row=(lane>>4)*4+reg (m); m-consecutive regs
    // -> float4 stores (16B-aligned: pt*64 + i*16 + rq multiple of 4)
    int cn = lane & 15;
    int rq = (lane >> 4) * 4;
    long outb = (long)n * OUT_IMG_STRIDE + pt * 64;
#pragma unroll
    for (int i = 0; i < 4; ++i) {
        int mb = i * 16 + rq;
#pragma unroll
        for (int j = 0; j < 4; ++j) {
            int cout = wn * 64 + j * 16 + cn;
            float bv = bias[cout];
            f32x4_t v = acc[i][j];
            v[0] += bv; v[1] += bv; v[2] += bv; v[3] += bv;
            *(f32x4_t*)&out[outb + (long)cout * PIX + mb] = v;
        }
    }
}

extern "C" void kernel_launch(void* const* d_in, const int* in_sizes, int n_in,
                              void* d_out, int out_size, void* d_ws, size_t ws_size,
                              hipStream_t stream) {
    const float* x    = (const float*)d_in[0];
    const float* wgt  = (const float*)d_in[1];
    const float* bias = (const float*)d_in[2];
    float* out = (float*)d_out;

    __hip_bfloat16* xpad = (__hip_bfloat16*)d_ws;                       // 55,115,776 B
    __hip_bfloat16* wt   = (__hip_bfloat16*)((char*)d_ws + 55115776);   // 1,179,648 B

    // pass 0: zero only the padded border (ws is re-poisoned before every call)
    border_zero_kernel<<<dim3((32 * 228 * 32 + 255) / 256), dim3(256), 0, stream>>>(xpad);

    // pass 1: NCHW fp32 -> padded NHWC bf16
    xform_kernel<<<dim3(N_IMG * 4 * 49), dim3(256), 0, stream>>>(x, xpad);

    // pass 2: binarize weights -> wt[cout][tap][c]
    wxform_kernel<<<dim3((C_OUT * K_TOT + 255) / 256), dim3(256), 0, stream>>>(wgt, wt);

    // pass 3: balanced-reuse implicit GEMM (49 px-tiles x 32 images, BN=256)
    gemm_kernel<<<dim3(N_IMG * 49), dim3(256), 0, stream>>>(xpad, wt, bias, out);
}